// Round 3
// baseline (1329.007 us; speedup 1.0000x reference)
//
#include <hip/hip_runtime.h>

// Problem constants
#define HID   4096
#define OUTF  4096
#define NTOK  8192          // B*S = 4*2048
#define PROJ_STRIDE 33554432ull  // NTOK*OUTF

typedef int   i32x4  __attribute__((ext_vector_type(4)));
typedef int   i32x16 __attribute__((ext_vector_type(16)));
typedef float f32x4  __attribute__((ext_vector_type(4)));

// ---------------------------------------------------------------------------
// Kernel W: int32 weights (values -8..7) -> int8 packed, 4 elems/thread
// ---------------------------------------------------------------------------
__global__ __launch_bounds__(256) void cvt_weights_i8(const int* __restrict__ w,
                                                      char* __restrict__ o,
                                                      int n4) {
    int i = blockIdx.x * blockDim.x + threadIdx.x;
    if (i < n4) {
        int4 v = ((const int4*)w)[i];
        int packed = (v.x & 255) | ((v.y & 255) << 8) |
                     ((v.z & 255) << 16) | (v.w << 24);
        ((int*)o)[i] = packed;
    }
}

// ---------------------------------------------------------------------------
// Kernel T: 64x64 f32 transpose of `left` (once)
// ---------------------------------------------------------------------------
__global__ __launch_bounds__(256) void transpose64(const float* __restrict__ in,
                                                   float* __restrict__ out) {
    int i = blockIdx.x * 256 + threadIdx.x;   // grid 16 * 256 = 4096
    int r = i >> 6, c = i & 63;
    out[c * 64 + r] = in[i];                  // out[l][m] = left[m][l]
}

// ---------------------------------------------------------------------------
// Kernel A: per-token transform + quantize. ONE WAVE PER TOKEN, 8x8 register
// tile per thread, ZERO __syncthreads.
//   - Wave DMA-stages its own X (16 KB, per-wave LDS region), vmcnt(0) only.
//   - leftT / right read from GLOBAL (32 KB total, L1-resident everywhere).
//   - Stage 1: acc[i][j] = sum_l leftT[l][8tm+i] * X[l][8tn+j]   (l ascending)
//   - T1^T overwrites the X region: row r holds T1[.][r]; 16B slot s of row r
//     stored at phys slot s ^ (r>>3)  -> uniform 8 lanes/bank-quad on both
//     write and read sides (write: lanes (tm,tn), quad ((2tm+h)^tn)&7 uniform;
//     read: 2 addrs/quad = free).
//   - Stage 2: acc[i][j] = sum_r T1[8tm+i][r] * right[r][8tn+j]  (r ascending)
//   - maxabs via 6x shfl_xor (wave-wide, no LDS, no barrier).
//   FMA chain order per output element identical to previous rounds ->
//   bit-identical xq (absmax must stay 0.046875).
// ---------------------------------------------------------------------------
__global__ __launch_bounds__(128) void transform_quant(
    const float* __restrict__ hs, const float* __restrict__ leftT,
    const float* __restrict__ right, char* __restrict__ xq,
    float* __restrict__ ascale) {
    __shared__ __align__(16) float Xw[2][4096];   // 16 KB per wave; X then T1^T

    const int wv   = threadIdx.x >> 6;
    const int lane = threadIdx.x & 63;
    const int t    = blockIdx.x * 2 + wv;
    const int tm   = lane >> 3;      // 0..7  (m-block)
    const int tn   = lane & 7;       // 0..7  (r/n-block)

    const float* X = hs + (size_t)t * HID;
    float* Tw = &Xw[wv][0];

    // Stage X into this wave's LDS region (16 DMA ops, linear layout).
    #pragma unroll
    for (int k = 0; k < 16; k++) {
        __builtin_amdgcn_global_load_lds(
            (const __attribute__((address_space(1))) void*)(X + k * 256 + lane * 4),
            (__attribute__((address_space(3))) void*)(Tw + k * 256 + lane * 4),
            16, 0, 0);
    }
    asm volatile("s_waitcnt vmcnt(0)" ::: "memory");

    float acc[8][8];
    #pragma unroll
    for (int i = 0; i < 8; i++)
        #pragma unroll
        for (int j = 0; j < 8; j++) acc[i][j] = 0.f;

    // Stage 1: T1[m][r] = sum_l left[m][l] * X[l][r]
    #pragma unroll 2
    for (int l = 0; l < 64; l++) {
        f32x4 x0 = *(const f32x4*)(Tw + l * 64 + tn * 8);
        f32x4 x1 = *(const f32x4*)(Tw + l * 64 + tn * 8 + 4);
        f32x4 l0 = *(const f32x4*)(leftT + l * 64 + tm * 8);
        f32x4 l1 = *(const f32x4*)(leftT + l * 64 + tm * 8 + 4);
        #pragma unroll
        for (int i = 0; i < 4; i++)
            #pragma unroll
            for (int j = 0; j < 4; j++) {
                acc[i][j]         = fmaf(l0[i], x0[j], acc[i][j]);
                acc[i][j + 4]     = fmaf(l0[i], x1[j], acc[i][j + 4]);
                acc[i + 4][j]     = fmaf(l1[i], x0[j], acc[i + 4][j]);
                acc[i + 4][j + 4] = fmaf(l1[i], x1[j], acc[i + 4][j + 4]);
            }
    }

    // Write T1^T into the same region (all X reads are data-predecessors of
    // every acc element, so dataflow guarantees reads complete first).
    // Row r = 8*tn + j; logical 16B slot s = 2*tm + h stored at s ^ tn.
    #pragma unroll
    for (int j = 0; j < 8; j++) {
        const int r = tn * 8 + j;
        f32x4 c0 = {acc[0][j], acc[1][j], acc[2][j], acc[3][j]};
        f32x4 c1 = {acc[4][j], acc[5][j], acc[6][j], acc[7][j]};
        *(f32x4*)(Tw + r * 64 + (((2 * tm + 0) ^ tn) << 2)) = c0;
        *(f32x4*)(Tw + r * 64 + (((2 * tm + 1) ^ tn) << 2)) = c1;
    }

    #pragma unroll
    for (int i = 0; i < 8; i++)
        #pragma unroll
        for (int j = 0; j < 8; j++) acc[i][j] = 0.f;

    // Stage 2: XT[m][n] = sum_r T1[m][r] * right[r][n]
    #pragma unroll 2
    for (int r = 0; r < 64; r++) {
        f32x4 t0 = *(const f32x4*)(Tw + r * 64 + (((2 * tm + 0) ^ (r >> 3)) << 2));
        f32x4 t1 = *(const f32x4*)(Tw + r * 64 + (((2 * tm + 1) ^ (r >> 3)) << 2));
        f32x4 r0 = *(const f32x4*)(right + r * 64 + tn * 8);
        f32x4 r1 = *(const f32x4*)(right + r * 64 + tn * 8 + 4);
        #pragma unroll
        for (int i = 0; i < 4; i++)
            #pragma unroll
            for (int j = 0; j < 4; j++) {
                acc[i][j]         = fmaf(t0[i], r0[j], acc[i][j]);
                acc[i][j + 4]     = fmaf(t0[i], r1[j], acc[i][j + 4]);
                acc[i + 4][j]     = fmaf(t1[i], r0[j], acc[i + 4][j]);
                acc[i + 4][j + 4] = fmaf(t1[i], r1[j], acc[i + 4][j + 4]);
            }
    }

    // Wave-wide maxabs (no barriers)
    float mx = 0.f;
    #pragma unroll
    for (int i = 0; i < 8; i++)
        #pragma unroll
        for (int j = 0; j < 8; j++) mx = fmaxf(mx, fabsf(acc[i][j]));
    #pragma unroll
    for (int d = 1; d < 64; d <<= 1) mx = fmaxf(mx, __shfl_xor(mx, d, 64));
    const float scale = fmaxf(mx * (1.0f / 7.0f), 1e-8f);

    // Quantize + pack int8x8
    char* dst = xq + (size_t)t * HID;
    #pragma unroll
    for (int i = 0; i < 8; i++) {
        int p0 = 0, p1 = 0;
        #pragma unroll
        for (int j = 0; j < 4; j++) {
            float q = rintf(acc[i][j] / scale);
            q = fminf(fmaxf(q, -8.f), 7.f);
            p0 |= ((int)q & 255) << (8 * j);
        }
        #pragma unroll
        for (int j = 4; j < 8; j++) {
            float q = rintf(acc[i][j] / scale);
            q = fminf(fmaxf(q, -8.f), 7.f);
            p1 |= ((int)q & 255) << (8 * (j - 4));
        }
        *(int2*)(dst + (tm * 8 + i) * 64 + tn * 8) = make_int2(p0, p1);
    }
    if (lane == 0) ascale[t] = scale;
}

// ---------------------------------------------------------------------------
// Kernel G: i8 MFMA GEMM, 128x128 tile, BK=128, mfma_i32_32x32x32_i8.
//   256 thr = 4 waves (2x2), wave tile 64x64 = 2x2 blocks of 32x32.
//   Double-buffered LDS 64 KiB -> 2 blocks/CU (implicit cross-block overlap).
//   Counted vmcnt(8): tile waited on was issued a full iteration earlier.
//   T2 XOR swizzle ((row&7)<<4), both sides. 2 barriers/iter ledger:
//   STAGE(t+1 -> buf^1) issued after barrier2(t-1) which is after all reads
//   of buf^1's previous contents completed (reads precede MFMA precede
//   barrier2). Gate vmcnt(8)+barrier1 => all waves' current tile landed.
// ---------------------------------------------------------------------------
#define GBM 128
#define GBK 128

#define GSTAGE(BUF, KT)                                                       \
  { _Pragma("unroll") for (int i_ = 0; i_ < 4; i_++) {                        \
      const int c_ = tid + i_ * 256;                                          \
      const int r_ = c_ >> 3;                                                 \
      const int s_ = ((c_ ^ r_) & 7) << 4;                                    \
      __builtin_amdgcn_global_load_lds(                                       \
          (const __attribute__((address_space(1))) void*)                     \
              (Ag + (size_t)r_ * HID + (KT) * GBK + s_),                      \
          (__attribute__((address_space(3))) void*)                           \
              (As + (BUF) * 16384 + c_ * 16), 16, 0, 0);                      \
    }                                                                         \
    _Pragma("unroll") for (int i_ = 0; i_ < 4; i_++) {                        \
      const int c_ = tid + i_ * 256;                                          \
      const int r_ = c_ >> 3;                                                 \
      const int s_ = ((c_ ^ r_) & 7) << 4;                                    \
      __builtin_amdgcn_global_load_lds(                                       \
          (const __attribute__((address_space(1))) void*)                     \
              (Bg + (size_t)r_ * HID + (KT) * GBK + s_),                      \
          (__attribute__((address_space(3))) void*)                           \
              (Bs + (BUF) * 16384 + c_ * 16), 16, 0, 0);                      \
    }                                                                         \
  }

__global__ __launch_bounds__(256, 2) void gemm_qkv(
    const char* __restrict__ xq, const float* __restrict__ ascale,
    const char* __restrict__ w8, const float* __restrict__ sq,
    const float* __restrict__ sk, const float* __restrict__ sv,
    float* __restrict__ out) {
    __shared__ __align__(16) char As[2 * 16384];   // 32 KB
    __shared__ __align__(16) char Bs[2 * 16384];   // 32 KB

    const int tid  = threadIdx.x;
    const int lane = tid & 63;
    const int wave = tid >> 6;
    const int wr   = wave >> 1;      // 2x2 wave grid, each wave 64x64
    const int wc   = wave & 1;
    const int l31  = lane & 31;
    const int kh   = lane >> 5;      // k-half within a 32-elem K step
    const int xk   = (l31 & 7) << 4; // swizzle term (row&7 == l31&7 always)

    // XCD-aware bijective swizzle: nwg = 6144 = 8 * 768
    const int wg   = blockIdx.x;
    const int swz  = (wg & 7) * 768 + (wg >> 3);
    const int proj = swz >> 11;          // 0..2
    const int rr   = swz & 2047;
    const int nb   = rr >> 6;            // 0..31 (mb fastest: shared B panel)
    const int mb   = rr & 63;            // 0..63

    const char* Ag = xq + (size_t)mb * GBM * HID;
    const char* Bg = w8 + (size_t)proj * ((size_t)OUTF * HID) +
                     (size_t)nb * GBM * HID;
    const float* wscale = (proj == 0) ? sq : ((proj == 1) ? sk : sv);

    i32x16 acc[2][2];
    #pragma unroll
    for (int i = 0; i < 2; i++)
        #pragma unroll
        for (int j = 0; j < 2; j++)
            #pragma unroll
            for (int e = 0; e < 16; e++) acc[i][j][e] = 0;

    GSTAGE(0, 0);   // prologue: tile 0 -> buf 0 (8 ops in flight)

    for (int kt = 0; kt < 32; ++kt) {
        const int cur = kt & 1;
        if (kt < 31) {
            GSTAGE(cur ^ 1, kt + 1);                        // 8 more ops
            asm volatile("s_waitcnt vmcnt(8)" ::: "memory"); // tile kt landed
        } else {
            asm volatile("s_waitcnt vmcnt(0)" ::: "memory");
        }
        __builtin_amdgcn_s_barrier();     // data-ready

        const char* Ab = As + cur * 16384;
        const char* Bb = Bs + cur * 16384;
        __builtin_amdgcn_s_setprio(1);
        #pragma unroll
        for (int ks = 0; ks < 4; ks++) {
            const int kb = ks * 32 + kh * 16;
            i32x4 a0 = *(const i32x4*)(Ab + (wr * 64 + l31) * GBK + (kb ^ xk));
            i32x4 a1 = *(const i32x4*)(Ab + (wr * 64 + 32 + l31) * GBK + (kb ^ xk));
            i32x4 b0 = *(const i32x4*)(Bb + (wc * 64 + l31) * GBK + (kb ^ xk));
            i32x4 b1 = *(const i32x4*)(Bb + (wc * 64 + 32 + l31) * GBK + (kb ^ xk));
            acc[0][0] = __builtin_amdgcn_mfma_i32_32x32x32_i8(a0, b0, acc[0][0], 0, 0, 0);
            acc[0][1] = __builtin_amdgcn_mfma_i32_32x32x32_i8(a0, b1, acc[0][1], 0, 0, 0);
            acc[1][0] = __builtin_amdgcn_mfma_i32_32x32x32_i8(a1, b0, acc[1][0], 0, 0, 0);
            acc[1][1] = __builtin_amdgcn_mfma_i32_32x32x32_i8(a1, b1, acc[1][1], 0, 0, 0);
        }
        __builtin_amdgcn_s_setprio(0);
        __builtin_amdgcn_s_barrier();     // retire (protects buf^1 overwrite)
    }

    // Epilogue: 32x32 C/D layout col=lane&31, row=(reg&3)+8*(reg>>2)+4*(lane>>5)
    const int rq = (lane >> 5) * 4;
    #pragma unroll
    for (int ib = 0; ib < 2; ib++)
        #pragma unroll
        for (int jb = 0; jb < 2; jb++) {
            #pragma unroll
            for (int reg = 0; reg < 16; reg++) {
                const int rl  = (reg & 3) + 8 * (reg >> 2) + rq;
                const int row = mb * GBM + wr * 64 + ib * 32 + rl;
                const int col = nb * GBM + wc * 64 + jb * 32 + l31;
                out[(size_t)proj * PROJ_STRIDE + (size_t)row * OUTF + col] =
                    (float)acc[ib][jb][reg] * ascale[row] * wscale[col];
            }
        }
}

// ---------------------------------------------------------------------------
// Launch
// ---------------------------------------------------------------------------
extern "C" void kernel_launch(void* const* d_in, const int* in_sizes, int n_in,
                              void* d_out, int out_size, void* d_ws, size_t ws_size,
                              hipStream_t stream) {
    const float* hs    = (const float*)d_in[0];
    const float* left  = (const float*)d_in[1];
    const float* right = (const float*)d_in[2];
    const int*   wq    = (const int*)d_in[3];
    const float* sq    = (const float*)d_in[4];
    const int*   wk    = (const int*)d_in[5];
    const float* sk    = (const float*)d_in[6];
    const int*   wv    = (const int*)d_in[7];
    const float* sv    = (const float*)d_in[8];
    float* out = (float*)d_out;

    // Workspace layout
    //   xq8    : NTOK*HID i8        = 33,554,432 B
    //   ascale : NTOK f32           =     32,768 B
    //   w8     : 3*OUTF*HID i8      = 50,331,648 B
    //   leftT  : 64*64 f32          =     16,384 B
    char*  xq8  = (char*)d_ws;
    float* ascl = (float*)((char*)d_ws + 33554432ull);
    char*  w8   = (char*)d_ws + 33587200ull;
    float* ltT  = (float*)((char*)d_ws + 83918848ull);

    const int nW = OUTF * HID;
    const int n4 = nW / 4;
    dim3 cblk(256), cgrd((n4 + 255) / 256);
    cvt_weights_i8<<<cgrd, cblk, 0, stream>>>(wq, w8 + 0ull * (size_t)nW, n4);
    cvt_weights_i8<<<cgrd, cblk, 0, stream>>>(wk, w8 + 1ull * (size_t)nW, n4);
    cvt_weights_i8<<<cgrd, cblk, 0, stream>>>(wv, w8 + 2ull * (size_t)nW, n4);

    transpose64<<<dim3(16), dim3(256), 0, stream>>>(left, ltT);

    transform_quant<<<dim3(NTOK / 2), dim3(128), 0, stream>>>(hs, ltT, right, xq8, ascl);

    gemm_qkv<<<dim3((NTOK / GBM) * (OUTF / GBM) * 3), dim3(256), 0, stream>>>(
        xq8, ascl, w8, sq, sk, sv, out);
}